// Round 6
// baseline (411.220 us; speedup 1.0000x reference)
//
#include <hip/hip_runtime.h>
#include <hip/hip_bf16.h>

typedef __hip_bfloat16 bf16;
typedef unsigned short u16t;
typedef unsigned int u32t;
typedef __attribute__((ext_vector_type(8))) short bf16x8_t;
typedef __attribute__((ext_vector_type(4))) float f32x4_t;

#define DEVI static __device__ __forceinline__

DEVI float u2f(u32t bits) { union { u32t u; float f; } v; v.u = bits; return v.f; }
DEVI float bflo(u32t u) { return u2f((u & 0xffffu) << 16); }
DEVI float bfhi(u32t u) { return u2f(u & 0xffff0000u); }
DEVI float bf2f(bf16 h) { return __bfloat162float(h); }
DEVI bf16 f2bf(float f) { return __float2bfloat16(f); }
DEVI u16t f2bfbits(float f) {
  bf16 h = __float2bfloat16(f);
  union { bf16 h; u16t u; } v; v.h = h; return v.u;
}

// Problem constants: x (2,8,56,56,128); windows (2,7,7) -> N=98; NW=512
#define TOK   50176
#define NWIN  512
#define NTOK  98
#define NHEAD 4
#define HDIM  32

// ---------------------------------------------------------------------------
__global__ __launch_bounds__(256) void cvt_k(const float* __restrict__ s,
                                             bf16* __restrict__ d, int n) {
  int i = blockIdx.x * 256 + threadIdx.x;
  if (i < n) d[i] = f2bf(s[i]);
}

// Bias matrix precompute: Bmat[h][i][j] = btab[relidx[i*98+j]*4 + h]
__global__ __launch_bounds__(256) void bias_k(const float* __restrict__ btab,
                                              const int* __restrict__ relidx,
                                              float* __restrict__ Bmat) {
  int idx = blockIdx.x * 256 + threadIdx.x;
  if (idx < NTOK * NTOK) {
    int r = relidx[idx] * NHEAD;
#pragma unroll
    for (int h = 0; h < NHEAD; h++)
      Bmat[h * NTOK * NTOK + idx] = btab[r + h];
  }
}

// ---------------------------------------------------------------------------
// LN1 (fp32 input, token order) + window partition -> bf16
// ---------------------------------------------------------------------------
__global__ __launch_bounds__(256) void ln1_k(
    const float* __restrict__ x, const float* __restrict__ w,
    const float* __restrict__ b, bf16* __restrict__ o)
{
  const int wave = threadIdx.x >> 6, lane = threadIdx.x & 63;
  const int t = blockIdx.x * 4 + wave;
  const int c = lane << 1;
  float2 xv = *(const float2*)(x + (size_t)t * 128 + c);
  float x0 = xv.x, x1 = xv.y;
  float s = x0 + x1, ss = x0 * x0 + x1 * x1;
#pragma unroll
  for (int m = 32; m; m >>= 1) { s += __shfl_xor(s, m); ss += __shfl_xor(ss, m); }
  float mean = s * 0.0078125f;
  float var = ss * 0.0078125f - mean * mean;
  float rstd = rsqrtf(var + 1e-5f);
  float y0 = (x0 - mean) * rstd * w[c]     + b[c];
  float y1 = (x1 - mean) * rstd * w[c + 1] + b[c + 1];
  int wi = t % 56; int r = t / 56;
  int hi_ = r % 56; r /= 56;
  int di = r & 7; int bi = r >> 3;
  int nw = ((bi * 4 + (di >> 1)) * 8 + hi_ / 7) * 8 + wi / 7;
  int n  = ((di & 1) * 7 + hi_ % 7) * 7 + wi % 7;
  u32t ov = ((u32t)f2bfbits(y1) << 16) | (u32t)f2bfbits(y0);
  *(u32t*)((u16t*)o + (size_t)(nw * NTOK + n) * 128 + c) = ov;
}

// ---------------------------------------------------------------------------
// LN2 (bf16 input, token order) -> bf16
// ---------------------------------------------------------------------------
__global__ __launch_bounds__(256) void ln2_k(
    const bf16* __restrict__ x, const float* __restrict__ w,
    const float* __restrict__ b, bf16* __restrict__ o)
{
  const int wave = threadIdx.x >> 6, lane = threadIdx.x & 63;
  const int t = blockIdx.x * 4 + wave;
  const int c = lane << 1;
  u32t u = *(const u32t*)((const u16t*)x + (size_t)t * 128 + c);
  float x0 = bflo(u), x1 = bfhi(u);
  float s = x0 + x1, ss = x0 * x0 + x1 * x1;
#pragma unroll
  for (int m = 32; m; m >>= 1) { s += __shfl_xor(s, m); ss += __shfl_xor(ss, m); }
  float mean = s * 0.0078125f;
  float var = ss * 0.0078125f - mean * mean;
  float rstd = rsqrtf(var + 1e-5f);
  float y0 = (x0 - mean) * rstd * w[c]     + b[c];
  float y1 = (x1 - mean) * rstd * w[c + 1] + b[c + 1];
  u32t ov = ((u32t)f2bfbits(y1) << 16) | (u32t)f2bfbits(y0);
  *(u32t*)((u16t*)o + (size_t)t * 128 + c) = ov;
}

// ---------------------------------------------------------------------------
// LDS-free direct GEMM: C[M,N] = A[M,K](bf16) @ W[N,K](bf16)^T + bias(fp32).
// Weights are L2-resident (<=128KB); A and B fragments are loaded straight
// from global as 16B/lane bf16x8 (pattern HW-verified in attention QK^T).
// No LDS, no barriers. Block = 4 independent waves, each owning 16 rows.
// MODE 0: +bias -> bf16                    (qkv)
// MODE 1: +bias +winrev +resX(fp32) -> bf16 (proj)
// ---------------------------------------------------------------------------
template <int MODE, int NT, int KS>   // N = NT*16, K = KS*32
__global__ __launch_bounds__(256) void gemm_direct_k(
    const bf16* __restrict__ A, const bf16* __restrict__ W,
    const float* __restrict__ bias, const float* __restrict__ resX,
    bf16* __restrict__ outB)
{
  const int tid = threadIdx.x;
  const int wv = tid >> 6, lane = tid & 63;
  const int q = lane >> 4, r16 = lane & 15;
  const int rowW = blockIdx.x * 64 + wv * 16;
  const int K = KS * 32, N = NT * 16;

  f32x4_t acc[NT];
#pragma unroll
  for (int nt = 0; nt < NT; nt++) acc[nt] = (f32x4_t){0.f, 0.f, 0.f, 0.f};

  const u16t* Ap = (const u16t*)A + (size_t)(rowW + r16) * K + (q << 3);
  const u16t* Wp = (const u16t*)W + (size_t)r16 * K + (q << 3);

#pragma unroll
  for (int ks = 0; ks < KS; ks++) {
    bf16x8_t a = *(const bf16x8_t*)(Ap + (ks << 5));
#pragma unroll
    for (int nt = 0; nt < NT; nt++) {
      bf16x8_t b = *(const bf16x8_t*)(Wp + (size_t)nt * 16 * K + (ks << 5));
      acc[nt] = __builtin_amdgcn_mfma_f32_16x16x32_bf16(a, b, acc[nt], 0, 0, 0);
    }
  }

  float bv[NT];
#pragma unroll
  for (int nt = 0; nt < NT; nt++) bv[nt] = bias[(nt << 4) + r16];

#pragma unroll
  for (int reg = 0; reg < 4; reg++) {
    int grow = rowW + (q << 2) + reg;
    if (MODE == 1) {
      // window-reverse: grow = nw*98+n -> token t
      int nw = grow / NTOK, n = grow - nw * NTOK;
      int wq = nw & 7, hq = (nw >> 3) & 7, dq = (nw >> 6) & 3, bb = nw >> 8;
      int wr = n % 7; int q7 = n / 7; int hr = q7 % 7, dr = q7 / 7;
      int tt = ((bb * 8 + dq * 2 + dr) * 56 + hq * 7 + hr) * 56 + wq * 7 + wr;
      size_t ob = (size_t)tt * 128;
#pragma unroll
      for (int nt = 0; nt < NT; nt++) {
        int col = (nt << 4) + r16;
        outB[ob + col] = f2bf(acc[nt][reg] + bv[nt] + resX[ob + col]);
      }
    } else {
      size_t ob = (size_t)grow * N;
#pragma unroll
      for (int nt = 0; nt < NT; nt++) {
        int col = (nt << 4) + r16;
        outB[ob + col] = f2bf(acc[nt][reg] + bv[nt]);
      }
    }
  }
}

// ---------------------------------------------------------------------------
// Fused MLP: out = x2 + (GELU(xn2@W1^T+b1))@W2^T + b2   (fp32 final output)
// 64-row blocks, 4 independent waves (16 rows each), NO barriers:
// h tile lives in wave-private LDS rows (stride 520 -> 2-way banks, free).
// fc1 in two 256-col passes (acc 16 frags); fc2 K=512 from LDS.
// ---------------------------------------------------------------------------
#define HSTR 520
__global__ __launch_bounds__(256) void mlp_k(
    const bf16* __restrict__ xn2, const bf16* __restrict__ w1,
    const float* __restrict__ b1, const bf16* __restrict__ w2,
    const float* __restrict__ b2, const bf16* __restrict__ x2,
    float* __restrict__ out)
{
  __shared__ short hs[64 * HSTR];
  const int tid = threadIdx.x;
  const int wv = tid >> 6, lane = tid & 63;
  const int q = lane >> 4, r16 = lane & 15;
  const int rowW = blockIdx.x * 64 + wv * 16;
  short* hw = &hs[(wv << 4) * HSTR];   // wave-private 16 rows

  // preload fc1 A-frags (K=128)
  bf16x8_t ax[4];
#pragma unroll
  for (int ks = 0; ks < 4; ks++)
    ax[ks] = *(const bf16x8_t*)((const u16t*)xn2 +
        (size_t)(rowW + r16) * 128 + (ks << 5) + (q << 3));

#pragma unroll
  for (int half = 0; half < 2; half++) {
    f32x4_t acc[16];
#pragma unroll
    for (int nt = 0; nt < 16; nt++) acc[nt] = (f32x4_t){0.f, 0.f, 0.f, 0.f};
#pragma unroll
    for (int ks = 0; ks < 4; ks++)
#pragma unroll
      for (int nt = 0; nt < 16; nt++) {
        int wrow = (half << 8) + (nt << 4) + r16;
        bf16x8_t b = *(const bf16x8_t*)((const u16t*)w1 +
            (size_t)wrow * 128 + (ks << 5) + (q << 3));
        acc[nt] = __builtin_amdgcn_mfma_f32_16x16x32_bf16(ax[ks], b, acc[nt], 0, 0, 0);
      }
#pragma unroll
    for (int nt = 0; nt < 16; nt++) {
      int col = (half << 8) + (nt << 4) + r16;
      float bvv = b1[col];
#pragma unroll
      for (int reg = 0; reg < 4; reg++) {
        float u = acc[nt][reg] + bvv;
        float g = 0.5f * u * (1.0f + erff(u * 0.70710678118654752f));
        hw[((q << 2) + reg) * HSTR + col] = (short)f2bfbits(g);
      }
    }
  }

  // fc2: K=512, A-frags from wave-private LDS h, B-frags from global W2
  f32x4_t a2[8];
#pragma unroll
  for (int nt = 0; nt < 8; nt++) a2[nt] = (f32x4_t){0.f, 0.f, 0.f, 0.f};
#pragma unroll
  for (int ks = 0; ks < 16; ks++) {
    bf16x8_t a = *(const bf16x8_t*)&hw[r16 * HSTR + (ks << 5) + (q << 3)];
#pragma unroll
    for (int nt = 0; nt < 8; nt++) {
      bf16x8_t b = *(const bf16x8_t*)((const u16t*)w2 +
          (size_t)((nt << 4) + r16) * 512 + (ks << 5) + (q << 3));
      a2[nt] = __builtin_amdgcn_mfma_f32_16x16x32_bf16(a, b, a2[nt], 0, 0, 0);
    }
  }

  float bv2[8];
#pragma unroll
  for (int nt = 0; nt < 8; nt++) bv2[nt] = b2[(nt << 4) + r16];
#pragma unroll
  for (int reg = 0; reg < 4; reg++) {
    size_t base = (size_t)(rowW + (q << 2) + reg) * 128;
#pragma unroll
    for (int nt = 0; nt < 8; nt++) {
      int col = (nt << 4) + r16;
      out[base + col] = a2[nt][reg] + bv2[nt] + bf2f(x2[base + col]);
    }
  }
}

// ---------------------------------------------------------------------------
// MFMA windowed attention. One block (4 waves) per (window, head).
// Per-wave 16-row P buffers (LDS 26KB -> 6 blocks/CU). No main-loop barriers.
// ---------------------------------------------------------------------------
#define PSTR 136
__global__ __launch_bounds__(256) void attn_mfma_k(
    const bf16* __restrict__ qkv, const float* __restrict__ Bmat,
    bf16* __restrict__ out)
{
  __shared__ short Vt[32 * PSTR];        // V^T [d][j], zero-padded j>=98
  __shared__ short Pw[4][16 * PSTR];     // per-wave P tile (16 rows)
  const int nw = blockIdx.x, h = blockIdx.y;
  const int tid = threadIdx.x;
  const int wv = tid >> 6, lane = tid & 63;
  const int q = lane >> 4, r16 = lane & 15;
  const float scale = 0.17677669529663687f;  // 32^-0.5

  // zero Vt cols [98,136)
  for (int idx = tid; idx < 32 * 38; idx += 256) {
    int d = idx / 38, j = 98 + idx % 38;
    Vt[d * PSTR + j] = 0;
  }
  // zero wave's P cols [112,128) (16 rows x 16 shorts)
  for (int idx = lane; idx < 16 * 8; idx += 64) {
    int r = idx >> 3, c = 112 + ((idx & 7) << 1);
    *(u32t*)&Pw[wv][r * PSTR + c] = 0;
  }
  // stage V transposed
  for (int idx = tid; idx < NTOK * 16; idx += 256) {
    int j = idx >> 4, d2 = (idx & 15) << 1;
    u32t uv = *(const u32t*)((const u16t*)qkv +
                             (size_t)(nw * NTOK + j) * 384 + 256 + h * 32 + d2);
    Vt[d2 * PSTR + j] = (short)(uv & 0xffffu);
    Vt[(d2 + 1) * PSTR + j] = (short)(uv >> 16);
  }
  __syncthreads();

  const int mt0 = wv;
  const bool has2 = (wv + 4) < 7;
  const int mt1 = has2 ? wv + 4 : wv;

  int i0 = mt0 * 16 + r16; if (i0 > NTOK - 1) i0 = NTOK - 1;
  int i1 = mt1 * 16 + r16; if (i1 > NTOK - 1) i1 = NTOK - 1;
  bf16x8_t aq0 = *(const bf16x8_t*)((const u16t*)qkv +
      (size_t)(nw * NTOK + i0) * 384 + h * 32 + (q << 3));
  bf16x8_t aq1 = *(const bf16x8_t*)((const u16t*)qkv +
      (size_t)(nw * NTOK + i1) * 384 + h * 32 + (q << 3));

  f32x4_t sc[2][7];
#pragma unroll
  for (int nt = 0; nt < 7; nt++) {
    int j = (nt << 4) + r16; if (j > NTOK - 1) j = NTOK - 1;
    bf16x8_t bk = *(const bf16x8_t*)((const u16t*)qkv +
        (size_t)(nw * NTOK + j) * 384 + 128 + h * 32 + (q << 3));
    sc[0][nt] = __builtin_amdgcn_mfma_f32_16x16x32_bf16(
        aq0, bk, (f32x4_t){0.f, 0.f, 0.f, 0.f}, 0, 0, 0);
    sc[1][nt] = __builtin_amdgcn_mfma_f32_16x16x32_bf16(
        aq1, bk, (f32x4_t){0.f, 0.f, 0.f, 0.f}, 0, 0, 0);
  }

  const float* Bh = Bmat + h * (NTOK * NTOK);
#pragma unroll
  for (int sel = 0; sel < 2; sel++) {
    if (sel == 1 && !has2) break;
    int mtile = sel ? mt1 : mt0;
    // softmax in registers (C-layout: col=r16, row=q*4+reg)
#pragma unroll
    for (int reg = 0; reg < 4; reg++) {
      int i = mtile * 16 + (q << 2) + reg;
      float s[7];
      float m = -3.0e38f;
#pragma unroll
      for (int nt = 0; nt < 7; nt++) {
        int j = (nt << 4) + r16;
        float v = sc[sel][nt][reg] * scale;
        v = (i < NTOK && j < NTOK) ? v + Bh[i * NTOK + j] : -1.0e30f;
        s[nt] = v;
        m = fmaxf(m, v);
      }
#pragma unroll
      for (int d = 8; d; d >>= 1) m = fmaxf(m, __shfl_xor(m, d));
      float sum = 0.f;
#pragma unroll
      for (int nt = 0; nt < 7; nt++) { s[nt] = __expf(s[nt] - m); sum += s[nt]; }
#pragma unroll
      for (int d = 8; d; d >>= 1) sum += __shfl_xor(sum, d);
      float inv = 1.f / sum;
#pragma unroll
      for (int nt = 0; nt < 7; nt++)
        Pw[wv][((q << 2) + reg) * PSTR + (nt << 4) + r16] =
            (short)f2bfbits(s[nt] * inv);
    }
    // PV (same-wave LDS RAW, no barrier)
    f32x4_t o0 = {0.f, 0.f, 0.f, 0.f}, o1 = {0.f, 0.f, 0.f, 0.f};
#pragma unroll
    for (int kt = 0; kt < 4; kt++) {
      bf16x8_t ap = *(const bf16x8_t*)&Pw[wv][r16 * PSTR + (kt << 5) + (q << 3)];
      bf16x8_t bv0 = *(const bf16x8_t*)&Vt[r16 * PSTR + (kt << 5) + (q << 3)];
      bf16x8_t bv1 = *(const bf16x8_t*)&Vt[(16 + r16) * PSTR + (kt << 5) + (q << 3)];
      o0 = __builtin_amdgcn_mfma_f32_16x16x32_bf16(ap, bv0, o0, 0, 0, 0);
      o1 = __builtin_amdgcn_mfma_f32_16x16x32_bf16(ap, bv1, o1, 0, 0, 0);
    }
#pragma unroll
    for (int reg = 0; reg < 4; reg++) {
      int i = mtile * 16 + (q << 2) + reg;
      if (i < NTOK) {
        size_t ob = (size_t)(nw * NTOK + i) * 128 + h * 32;
        out[ob + r16] = f2bf(o0[reg]);
        out[ob + 16 + r16] = f2bf(o1[reg]);
      }
    }
  }
}

// ---------------------------------------------------------------------------
extern "C" void kernel_launch(void* const* d_in, const int* in_sizes, int n_in,
                              void* d_out, int out_size, void* d_ws, size_t ws_size,
                              hipStream_t stream) {
  const float* x      = (const float*)d_in[0];
  const float* n1w    = (const float*)d_in[1];
  const float* n1b    = (const float*)d_in[2];
  const float* qkv_w  = (const float*)d_in[3];
  const float* qkv_b  = (const float*)d_in[4];
  const float* btab   = (const float*)d_in[5];
  const float* proj_w = (const float*)d_in[6];
  const float* proj_b = (const float*)d_in[7];
  const float* n2w    = (const float*)d_in[8];
  const float* n2b    = (const float*)d_in[9];
  const float* fc1_w  = (const float*)d_in[10];
  const float* fc1_b  = (const float*)d_in[11];
  const float* fc2_w  = (const float*)d_in[12];
  const float* fc2_b  = (const float*)d_in[13];
  const int*   relidx = (const int*)d_in[14];

  // Buffer plan (A = 50176*128*2 B):
  //   d_out scratch: xw = attn = d_out[0,A) (dead before final fp32 write)
  //   ws: qkv ws[0,3A) -> after attn: x2 ws[0,A), xn2 ws[A,2A)
  //       weights bf16 at [3A, +384KB), Bmat fp32 after (154KB). Peak ~39MB.
  const size_t Asz = (size_t)TOK * 128 * 2;
  char* ws = (char*)d_ws;
  bf16* xw    = (bf16*)d_out;
  bf16* attn  = (bf16*)d_out;
  bf16* qkv   = (bf16*)(ws);
  bf16* x2    = (bf16*)(ws);
  bf16* xn2   = (bf16*)(ws + Asz);
  bf16* wbf   = (bf16*)(ws + 3 * Asz);
  bf16* qkvw16  = wbf;               // 49152
  bf16* projw16 = wbf + 49152;       // 16384
  bf16* fc1w16  = wbf + 65536;       // 65536
  bf16* fc2w16  = wbf + 131072;      // 65536
  float* Bmat = (float*)(ws + 3 * Asz + 393216);  // 4*98*98 fp32
  float* out  = (float*)d_out;

  // 0. weight conversion + bias matrix
  cvt_k<<<192, 256, 0, stream>>>(qkv_w, qkvw16, 49152);
  cvt_k<<<64, 256, 0, stream>>>(proj_w, projw16, 16384);
  cvt_k<<<256, 256, 0, stream>>>(fc1_w, fc1w16, 65536);
  cvt_k<<<256, 256, 0, stream>>>(fc2_w, fc2w16, 65536);
  bias_k<<<38, 256, 0, stream>>>(btab, relidx, Bmat);
  // 1. LN1 + window partition
  ln1_k<<<TOK / 4, 256, 0, stream>>>(x, n1w, n1b, xw);
  // 2. QKV: (50176,128) @ (384,128)^T  — LDS-free direct MFMA
  gemm_direct_k<0, 24, 4><<<TOK / 64, 256, 0, stream>>>(
      xw, qkvw16, qkv_b, nullptr, qkv);
  // 3. MFMA windowed attention
  attn_mfma_k<<<dim3(NWIN, NHEAD), 256, 0, stream>>>(qkv, Bmat, attn);
  // 4. proj + window reverse + residual(x fp32) -> x2 bf16 (token order)
  gemm_direct_k<1, 8, 4><<<TOK / 64, 256, 0, stream>>>(
      attn, projw16, proj_b, x, x2);
  // 5. LN2
  ln2_k<<<TOK / 4, 256, 0, stream>>>(x2, n2w, n2b, xn2);
  // 6. fused MLP (fc1 + GELU + fc2 + residual) -> final fp32 output
  mlp_k<<<TOK / 64, 256, 0, stream>>>(
      xn2, fc1w16, fc1_b, fc2w16, fc2_b, x2, out);
}

// Round 7
// 305.563 us; speedup vs baseline: 1.3458x; 1.3458x over previous
//
#include <hip/hip_runtime.h>
#include <hip/hip_bf16.h>

typedef __hip_bfloat16 bf16;
typedef unsigned short u16t;
typedef unsigned int u32t;
typedef __attribute__((ext_vector_type(8))) short bf16x8_t;
typedef __attribute__((ext_vector_type(4))) float f32x4_t;

#define DEVI static __device__ __forceinline__

DEVI float u2f(u32t bits) { union { u32t u; float f; } v; v.u = bits; return v.f; }
DEVI float bflo(u32t u) { return u2f((u & 0xffffu) << 16); }
DEVI float bfhi(u32t u) { return u2f(u & 0xffff0000u); }
DEVI float sh2f(short s) { return u2f(((u32t)(u16t)s) << 16); }
DEVI float bf2f(bf16 h) { return __bfloat162float(h); }
DEVI bf16 f2bf(float f) { return __float2bfloat16(f); }
DEVI u16t f2bfbits(float f) {
  bf16 h = __float2bfloat16(f);
  union { bf16 h; u16t u; } v; v.h = h; return v.u;
}

// async global->LDS, 16B per lane. LDS dest must be wave-uniform base + lane*16.
DEVI void gl_lds16(const void* g, void* l) {
  __builtin_amdgcn_global_load_lds(
      (const __attribute__((address_space(1))) unsigned int*)g,
      (__attribute__((address_space(3))) unsigned int*)l, 16, 0, 0);
}

// Problem constants: x (2,8,56,56,128); windows (2,7,7) -> N=98; NW=512
#define TOK   50176
#define NWIN  512
#define NTOK  98
#define NHEAD 4
#define HDIM  32

// ---------------------------------------------------------------------------
// All four weight matrices fp32 -> bf16 in one launch (dest contiguous).
// ---------------------------------------------------------------------------
__global__ __launch_bounds__(256) void cvt4_k(
    const float* __restrict__ a, const float* __restrict__ b,
    const float* __restrict__ c, const float* __restrict__ d,
    bf16* __restrict__ o) {
  int i = blockIdx.x * 256 + threadIdx.x;
  const float* s; int off;
  if (i < 49152)       { s = a; off = 0; }
  else if (i < 65536)  { s = b; off = 49152; }
  else if (i < 131072) { s = c; off = 65536; }
  else                 { s = d; off = 131072; }
  o[i] = f2bf(s[i - off]);
}

// Bias matrix precompute: Bmat[h][i][j] = btab[relidx[i*98+j]*4 + h]
__global__ __launch_bounds__(256) void bias_k(const float* __restrict__ btab,
                                              const int* __restrict__ relidx,
                                              float* __restrict__ Bmat) {
  int idx = blockIdx.x * 256 + threadIdx.x;
  if (idx < NTOK * NTOK) {
    int r = relidx[idx] * NHEAD;
#pragma unroll
    for (int h = 0; h < NHEAD; h++)
      Bmat[h * NTOK * NTOK + idx] = btab[r + h];
  }
}

// ---------------------------------------------------------------------------
// LN1 (fp32 input, token order) + window partition -> bf16
// ---------------------------------------------------------------------------
__global__ __launch_bounds__(256) void ln1_k(
    const float* __restrict__ x, const float* __restrict__ w,
    const float* __restrict__ b, bf16* __restrict__ o)
{
  const int wave = threadIdx.x >> 6, lane = threadIdx.x & 63;
  const int t = blockIdx.x * 4 + wave;
  const int c = lane << 1;
  float2 xv = *(const float2*)(x + (size_t)t * 128 + c);
  float x0 = xv.x, x1 = xv.y;
  float s = x0 + x1, ss = x0 * x0 + x1 * x1;
#pragma unroll
  for (int m = 32; m; m >>= 1) { s += __shfl_xor(s, m); ss += __shfl_xor(ss, m); }
  float mean = s * 0.0078125f;
  float var = ss * 0.0078125f - mean * mean;
  float rstd = rsqrtf(var + 1e-5f);
  float y0 = (x0 - mean) * rstd * w[c]     + b[c];
  float y1 = (x1 - mean) * rstd * w[c + 1] + b[c + 1];
  int wi = t % 56; int r = t / 56;
  int hi_ = r % 56; r /= 56;
  int di = r & 7; int bi = r >> 3;
  int nw = ((bi * 4 + (di >> 1)) * 8 + hi_ / 7) * 8 + wi / 7;
  int n  = ((di & 1) * 7 + hi_ % 7) * 7 + wi % 7;
  u32t ov = ((u32t)f2bfbits(y1) << 16) | (u32t)f2bfbits(y0);
  *(u32t*)((u16t*)o + (size_t)(nw * NTOK + n) * 128 + c) = ov;
}

// ---------------------------------------------------------------------------
// LN2 (bf16 input, token order) -> bf16
// ---------------------------------------------------------------------------
__global__ __launch_bounds__(256) void ln2_k(
    const bf16* __restrict__ x, const float* __restrict__ w,
    const float* __restrict__ b, bf16* __restrict__ o)
{
  const int wave = threadIdx.x >> 6, lane = threadIdx.x & 63;
  const int t = blockIdx.x * 4 + wave;
  const int c = lane << 1;
  u32t u = *(const u32t*)((const u16t*)x + (size_t)t * 128 + c);
  float x0 = bflo(u), x1 = bfhi(u);
  float s = x0 + x1, ss = x0 * x0 + x1 * x1;
#pragma unroll
  for (int m = 32; m; m >>= 1) { s += __shfl_xor(s, m); ss += __shfl_xor(ss, m); }
  float mean = s * 0.0078125f;
  float var = ss * 0.0078125f - mean * mean;
  float rstd = rsqrtf(var + 1e-5f);
  float y0 = (x0 - mean) * rstd * w[c]     + b[c];
  float y1 = (x1 - mean) * rstd * w[c + 1] + b[c + 1];
  u32t ov = ((u32t)f2bfbits(y1) << 16) | (u32t)f2bfbits(y0);
  *(u32t*)((u16t*)o + (size_t)t * 128 + c) = ov;
}

// ---------------------------------------------------------------------------
// MFMA GEMM: C[M,N] = A[M,K](bf16) @ W[N,K](bf16)^T + bias(fp32).
// 128x64 tile, BK=64, 4 waves. Staging via global_load_lds width=16 with an
// XOR chunk swizzle (chunk ^= row&7) applied on the global source -> LDS
// stride stays 64 (lane-ordered, required by global_load_lds) AND the
// ds_read_b128 fragment reads hit all 8 chunk groups uniformly (conflict-free).
// Epilogue (MODES 0/1/2): C-tile staged into the dead A-LDS buffer, written
// out cooperatively as dwordx4 (coalesced); MODE 1 residual read as float4.
// MODE 0: +bias -> bf16; 1: +bias+winrev+resX(f32) -> bf16;
// MODE 2: +bias+GELU -> bf16; 3: +bias+resB2(bf16) -> fp32 (final, scalar)
// ---------------------------------------------------------------------------
template <int MODE>
__global__ __launch_bounds__(256) void gemm_mfma_k(
    const bf16* __restrict__ A, const bf16* __restrict__ W,
    const float* __restrict__ bias, const float* __restrict__ resX,
    const bf16* __restrict__ resB2, bf16* __restrict__ outB,
    float* __restrict__ outF, int N, int K)
{
  __shared__ short As[128 * 64];
  __shared__ short Bs[64 * 64];
  const int tid = threadIdx.x;
  const int rowBase = blockIdx.y << 7;
  const int colBase = blockIdx.x << 6;
  const int wv = tid >> 6, lane = tid & 63;
  const int q = lane >> 4, r16 = lane & 15;
  const int mB = wv << 5;

  f32x4_t acc[2][4];
#pragma unroll
  for (int i = 0; i < 2; i++)
#pragma unroll
    for (int j = 0; j < 4; j++) acc[i][j] = (f32x4_t){0.f, 0.f, 0.f, 0.f};

  for (int k0 = 0; k0 < K; k0 += 64) {
    // A-tile 128x64: 1024 16B-chunks, 4/thread; source chunk XOR-swizzled
#pragma unroll
    for (int t = 0; t < 4; t++) {
      int f = tid + (t << 8);
      int row = f >> 3, cs = (f & 7) ^ (row & 7);
      gl_lds16((const u16t*)A + (size_t)(rowBase + row) * K + k0 + (cs << 3),
               &As[f << 3]);
    }
    // B-tile 64x64: 512 chunks, 2/thread
#pragma unroll
    for (int t = 0; t < 2; t++) {
      int f = tid + (t << 8);
      int row = f >> 3, cs = (f & 7) ^ (row & 7);
      gl_lds16((const u16t*)W + (size_t)(colBase + row) * K + k0 + (cs << 3),
               &Bs[f << 3]);
    }
    __syncthreads();
#pragma unroll
    for (int ks = 0; ks < 2; ks++) {
      bf16x8_t af[2], bfr[4];
#pragma unroll
      for (int mt = 0; mt < 2; mt++) {
        int row = mB + (mt << 4) + r16;
        int ch = ((ks << 2) + q) ^ (row & 7);
        af[mt] = *(const bf16x8_t*)&As[(row << 6) + (ch << 3)];
      }
#pragma unroll
      for (int nt = 0; nt < 4; nt++) {
        int row = (nt << 4) + r16;
        int ch = ((ks << 2) + q) ^ (row & 7);
        bfr[nt] = *(const bf16x8_t*)&Bs[(row << 6) + (ch << 3)];
      }
#pragma unroll
      for (int mt = 0; mt < 2; mt++)
#pragma unroll
        for (int nt = 0; nt < 4; nt++)
          acc[mt][nt] = __builtin_amdgcn_mfma_f32_16x16x32_bf16(
              af[mt], bfr[nt], acc[mt][nt], 0, 0, 0);
    }
    __syncthreads();
  }

  float bv[4];
#pragma unroll
  for (int nt = 0; nt < 4; nt++) bv[nt] = bias[colBase + (nt << 4) + r16];

  if (MODE == 3) {
    // final fp32 output + bf16 residual, direct scalar stores
#pragma unroll
    for (int mt = 0; mt < 2; mt++)
#pragma unroll
      for (int reg = 0; reg < 4; reg++) {
        int grow = rowBase + mB + (mt << 4) + (q << 2) + reg;
        size_t ob = (size_t)grow * N;
#pragma unroll
        for (int nt = 0; nt < 4; nt++) {
          int gcol = colBase + (nt << 4) + r16;
          outF[ob + gcol] = acc[mt][nt][reg] + bv[nt] + bf2f(resB2[ob + gcol]);
        }
      }
    return;
  }

  // MODES 0/1/2: stage C (bf16, +bias, +GELU for MODE 2) into As, then
  // cooperative coalesced write-out.
#pragma unroll
  for (int mt = 0; mt < 2; mt++)
#pragma unroll
    for (int reg = 0; reg < 4; reg++) {
      int lrow = mB + (mt << 4) + (q << 2) + reg;
#pragma unroll
      for (int nt = 0; nt < 4; nt++) {
        float v = acc[mt][nt][reg] + bv[nt];
        if (MODE == 2) v = 0.5f * v * (1.0f + erff(v * 0.70710678118654752f));
        As[(lrow << 6) + (nt << 4) + r16] = (short)f2bfbits(v);
      }
    }
  __syncthreads();
#pragma unroll
  for (int t = 0; t < 4; t++) {
    int f = tid + (t << 8);
    int row = f >> 3, c8 = (f & 7) << 3;
    if (MODE == 1) {
      int grow = rowBase + row;
      int nw = grow / NTOK, n = grow - nw * NTOK;
      int wq = nw & 7, hq = (nw >> 3) & 7, dq = (nw >> 6) & 3, bb = nw >> 8;
      int wr = n % 7; int q7 = n / 7; int hr = q7 % 7, dr = q7 / 7;
      int tt = ((bb * 8 + dq * 2 + dr) * 56 + hq * 7 + hr) * 56 + wq * 7 + wr;
      size_t ob = (size_t)tt * 128 + colBase + c8;
      float4 r0 = *(const float4*)(resX + ob);
      float4 r1 = *(const float4*)(resX + ob + 4);
      const short* cs = &As[(row << 6) + c8];
      u16t pk[8];
      pk[0] = f2bfbits(sh2f(cs[0]) + r0.x); pk[1] = f2bfbits(sh2f(cs[1]) + r0.y);
      pk[2] = f2bfbits(sh2f(cs[2]) + r0.z); pk[3] = f2bfbits(sh2f(cs[3]) + r0.w);
      pk[4] = f2bfbits(sh2f(cs[4]) + r1.x); pk[5] = f2bfbits(sh2f(cs[5]) + r1.y);
      pk[6] = f2bfbits(sh2f(cs[6]) + r1.z); pk[7] = f2bfbits(sh2f(cs[7]) + r1.w);
      *(uint4*)((u16t*)outB + ob) = *(const uint4*)pk;
    } else {
      size_t ob = (size_t)(rowBase + row) * N + colBase + c8;
      *(uint4*)((u16t*)outB + ob) = *(const uint4*)&As[(row << 6) + c8];
    }
  }
}

// ---------------------------------------------------------------------------
// MFMA windowed attention. One block (4 waves) per (window, head).
// Per-wave 16-row P buffers (LDS 26KB -> 6 blocks/CU). No main-loop barriers.
// ---------------------------------------------------------------------------
#define PSTR 136
__global__ __launch_bounds__(256) void attn_mfma_k(
    const bf16* __restrict__ qkv, const float* __restrict__ Bmat,
    bf16* __restrict__ out)
{
  __shared__ short Vt[32 * PSTR];        // V^T [d][j], zero-padded j>=98
  __shared__ short Pw[4][16 * PSTR];     // per-wave P tile (16 rows)
  const int nw = blockIdx.x, h = blockIdx.y;
  const int tid = threadIdx.x;
  const int wv = tid >> 6, lane = tid & 63;
  const int q = lane >> 4, r16 = lane & 15;
  const float scale = 0.17677669529663687f;  // 32^-0.5

  for (int idx = tid; idx < 32 * 38; idx += 256) {
    int d = idx / 38, j = 98 + idx % 38;
    Vt[d * PSTR + j] = 0;
  }
  for (int idx = lane; idx < 16 * 8; idx += 64) {
    int r = idx >> 3, c = 112 + ((idx & 7) << 1);
    *(u32t*)&Pw[wv][r * PSTR + c] = 0;
  }
  for (int idx = tid; idx < NTOK * 16; idx += 256) {
    int j = idx >> 4, d2 = (idx & 15) << 1;
    u32t uv = *(const u32t*)((const u16t*)qkv +
                             (size_t)(nw * NTOK + j) * 384 + 256 + h * 32 + d2);
    Vt[d2 * PSTR + j] = (short)(uv & 0xffffu);
    Vt[(d2 + 1) * PSTR + j] = (short)(uv >> 16);
  }
  __syncthreads();

  const int mt0 = wv;
  const bool has2 = (wv + 4) < 7;
  const int mt1 = has2 ? wv + 4 : wv;

  int i0 = mt0 * 16 + r16; if (i0 > NTOK - 1) i0 = NTOK - 1;
  int i1 = mt1 * 16 + r16; if (i1 > NTOK - 1) i1 = NTOK - 1;
  bf16x8_t aq0 = *(const bf16x8_t*)((const u16t*)qkv +
      (size_t)(nw * NTOK + i0) * 384 + h * 32 + (q << 3));
  bf16x8_t aq1 = *(const bf16x8_t*)((const u16t*)qkv +
      (size_t)(nw * NTOK + i1) * 384 + h * 32 + (q << 3));

  f32x4_t sc[2][7];
#pragma unroll
  for (int nt = 0; nt < 7; nt++) {
    int j = (nt << 4) + r16; if (j > NTOK - 1) j = NTOK - 1;
    bf16x8_t bk = *(const bf16x8_t*)((const u16t*)qkv +
        (size_t)(nw * NTOK + j) * 384 + 128 + h * 32 + (q << 3));
    sc[0][nt] = __builtin_amdgcn_mfma_f32_16x16x32_bf16(
        aq0, bk, (f32x4_t){0.f, 0.f, 0.f, 0.f}, 0, 0, 0);
    sc[1][nt] = __builtin_amdgcn_mfma_f32_16x16x32_bf16(
        aq1, bk, (f32x4_t){0.f, 0.f, 0.f, 0.f}, 0, 0, 0);
  }

  const float* Bh = Bmat + h * (NTOK * NTOK);
#pragma unroll
  for (int sel = 0; sel < 2; sel++) {
    if (sel == 1 && !has2) break;
    int mtile = sel ? mt1 : mt0;
#pragma unroll
    for (int reg = 0; reg < 4; reg++) {
      int i = mtile * 16 + (q << 2) + reg;
      float s[7];
      float m = -3.0e38f;
#pragma unroll
      for (int nt = 0; nt < 7; nt++) {
        int j = (nt << 4) + r16;
        float v = sc[sel][nt][reg] * scale;
        v = (i < NTOK && j < NTOK) ? v + Bh[i * NTOK + j] : -1.0e30f;
        s[nt] = v;
        m = fmaxf(m, v);
      }
#pragma unroll
      for (int d = 8; d; d >>= 1) m = fmaxf(m, __shfl_xor(m, d));
      float sum = 0.f;
#pragma unroll
      for (int nt = 0; nt < 7; nt++) { s[nt] = __expf(s[nt] - m); sum += s[nt]; }
#pragma unroll
      for (int d = 8; d; d >>= 1) sum += __shfl_xor(sum, d);
      float inv = 1.f / sum;
#pragma unroll
      for (int nt = 0; nt < 7; nt++)
        Pw[wv][((q << 2) + reg) * PSTR + (nt << 4) + r16] =
            (short)f2bfbits(s[nt] * inv);
    }
    f32x4_t o0 = {0.f, 0.f, 0.f, 0.f}, o1 = {0.f, 0.f, 0.f, 0.f};
#pragma unroll
    for (int kt = 0; kt < 4; kt++) {
      bf16x8_t ap = *(const bf16x8_t*)&Pw[wv][r16 * PSTR + (kt << 5) + (q << 3)];
      bf16x8_t bv0 = *(const bf16x8_t*)&Vt[r16 * PSTR + (kt << 5) + (q << 3)];
      bf16x8_t bv1 = *(const bf16x8_t*)&Vt[(16 + r16) * PSTR + (kt << 5) + (q << 3)];
      o0 = __builtin_amdgcn_mfma_f32_16x16x32_bf16(ap, bv0, o0, 0, 0, 0);
      o1 = __builtin_amdgcn_mfma_f32_16x16x32_bf16(ap, bv1, o1, 0, 0, 0);
    }
#pragma unroll
    for (int reg = 0; reg < 4; reg++) {
      int i = mtile * 16 + (q << 2) + reg;
      if (i < NTOK) {
        size_t ob = (size_t)(nw * NTOK + i) * 128 + h * 32;
        out[ob + r16] = f2bf(o0[reg]);
        out[ob + 16 + r16] = f2bf(o1[reg]);
      }
    }
  }
}

// ---------------------------------------------------------------------------
extern "C" void kernel_launch(void* const* d_in, const int* in_sizes, int n_in,
                              void* d_out, int out_size, void* d_ws, size_t ws_size,
                              hipStream_t stream) {
  const float* x      = (const float*)d_in[0];
  const float* n1w    = (const float*)d_in[1];
  const float* n1b    = (const float*)d_in[2];
  const float* qkv_w  = (const float*)d_in[3];
  const float* qkv_b  = (const float*)d_in[4];
  const float* btab   = (const float*)d_in[5];
  const float* proj_w = (const float*)d_in[6];
  const float* proj_b = (const float*)d_in[7];
  const float* n2w    = (const float*)d_in[8];
  const float* n2b    = (const float*)d_in[9];
  const float* fc1_w  = (const float*)d_in[10];
  const float* fc1_b  = (const float*)d_in[11];
  const float* fc2_w  = (const float*)d_in[12];
  const float* fc2_b  = (const float*)d_in[13];
  const int*   relidx = (const int*)d_in[14];

  // Buffer plan (A = 50176*128*2 B): d_out scratch for xw/attn;
  // ws: qkv [0,3A) -> x2 [0,A), xn2 [A,2A), hmid [2A,3A);
  // weights bf16 at 3A (384KB), Bmat fp32 after (154KB). Peak ~39MB.
  const size_t Asz = (size_t)TOK * 128 * 2;
  char* ws = (char*)d_ws;
  bf16* xw    = (bf16*)d_out;
  bf16* attn  = (bf16*)d_out;
  bf16* qkv   = (bf16*)(ws);
  bf16* x2    = (bf16*)(ws);
  bf16* xn2   = (bf16*)(ws + Asz);
  bf16* hmid  = (bf16*)(ws + 2 * Asz);
  bf16* wbf   = (bf16*)(ws + 3 * Asz);
  bf16* qkvw16  = wbf;               // 49152
  bf16* projw16 = wbf + 49152;       // 16384
  bf16* fc1w16  = wbf + 65536;       // 65536
  bf16* fc2w16  = wbf + 131072;      // 65536
  float* Bmat = (float*)(ws + 3 * Asz + 393216);  // 4*98*98 fp32
  float* out  = (float*)d_out;

  // 0. weight conversion (single launch) + bias matrix
  cvt4_k<<<768, 256, 0, stream>>>(qkv_w, proj_w, fc1_w, fc2_w, wbf);
  bias_k<<<38, 256, 0, stream>>>(btab, relidx, Bmat);
  // 1. LN1 + window partition
  ln1_k<<<TOK / 4, 256, 0, stream>>>(x, n1w, n1b, xw);
  // 2. QKV: (50176,128) @ (384,128)^T
  gemm_mfma_k<0><<<dim3(6, TOK / 128), 256, 0, stream>>>(
      xw, qkvw16, qkv_b, nullptr, nullptr, qkv, nullptr, 384, 128);
  // 3. MFMA windowed attention
  attn_mfma_k<<<dim3(NWIN, NHEAD), 256, 0, stream>>>(qkv, Bmat, attn);
  // 4. proj + window reverse + residual(x fp32) -> x2 bf16 (token order)
  gemm_mfma_k<1><<<dim3(2, TOK / 128), 256, 0, stream>>>(
      attn, projw16, proj_b, x, nullptr, x2, nullptr, 128, 128);
  // 5. LN2
  ln2_k<<<TOK / 4, 256, 0, stream>>>(x2, n2w, n2b, xn2);
  // 6/7. MLP in 4 token chunks (hmid reuse keeps ws at 3A)
  const int MC = TOK / 4;  // 12544 rows per chunk
  for (int c = 0; c < 4; c++) {
    gemm_mfma_k<2><<<dim3(8, MC / 128), 256, 0, stream>>>(
        xn2 + (size_t)c * MC * 128, fc1w16, fc1_b, nullptr, nullptr,
        hmid, nullptr, 512, 128);
    gemm_mfma_k<3><<<dim3(2, MC / 128), 256, 0, stream>>>(
        hmid, fc2w16, fc2_b, nullptr, x2 + (size_t)c * MC * 128,
        nullptr, out + (size_t)c * MC * 128, 128, 512);
  }
}

// Round 8
// 238.484 us; speedup vs baseline: 1.7243x; 1.2813x over previous
//
#include <hip/hip_runtime.h>
#include <hip/hip_bf16.h>

typedef __hip_bfloat16 bf16;
typedef unsigned short u16t;
typedef unsigned int u32t;
typedef __attribute__((ext_vector_type(8))) short bf16x8_t;
typedef __attribute__((ext_vector_type(4))) float f32x4_t;

#define DEVI static __device__ __forceinline__

DEVI float u2f(u32t bits) { union { u32t u; float f; } v; v.u = bits; return v.f; }
DEVI float bflo(u32t u) { return u2f((u & 0xffffu) << 16); }
DEVI float bfhi(u32t u) { return u2f(u & 0xffff0000u); }
DEVI float sh2f(short s) { return u2f(((u32t)(u16t)s) << 16); }
DEVI float bf2f(bf16 h) { return __bfloat162float(h); }
DEVI bf16 f2bf(float f) { return __float2bfloat16(f); }
DEVI u16t f2bfbits(float f) {
  bf16 h = __float2bfloat16(f);
  union { bf16 h; u16t u; } v; v.h = h; return v.u;
}

// async global->LDS, 16B per lane. LDS dest must be wave-uniform base + lane*16.
DEVI void gl_lds16(const void* g, void* l) {
  __builtin_amdgcn_global_load_lds(
      (const __attribute__((address_space(1))) unsigned int*)g,
      (__attribute__((address_space(3))) unsigned int*)l, 16, 0, 0);
}

// Problem constants: x (2,8,56,56,128); windows (2,7,7) -> N=98; NW=512
#define TOK   50176
#define NWIN  512
#define NTOK  98
#define NHEAD 4
#define HDIM  32

// ---------------------------------------------------------------------------
// All four weight matrices fp32 -> bf16 in one launch (dest contiguous).
// ---------------------------------------------------------------------------
__global__ __launch_bounds__(256) void cvt4_k(
    const float* __restrict__ a, const float* __restrict__ b,
    const float* __restrict__ c, const float* __restrict__ d,
    bf16* __restrict__ o) {
  int i = blockIdx.x * 256 + threadIdx.x;
  const float* s; int off;
  if (i < 49152)       { s = a; off = 0; }
  else if (i < 65536)  { s = b; off = 49152; }
  else if (i < 131072) { s = c; off = 65536; }
  else                 { s = d; off = 131072; }
  o[i] = f2bf(s[i - off]);
}

// Transposed bias matrix: BmatT[h][j][i] = btab[relidx[i*98+j]*4+h].
// Row-padded to 112 floats so float4 loads at i in [96,112) stay in-bounds.
__global__ __launch_bounds__(256) void bias_k(const float* __restrict__ btab,
                                              const int* __restrict__ relidx,
                                              float* __restrict__ BmatT) {
  int idx = blockIdx.x * 256 + threadIdx.x;
  if (idx < NTOK * NTOK) {
    int i = idx / NTOK, j = idx - i * NTOK;
    int r = relidx[idx] * NHEAD;
#pragma unroll
    for (int h = 0; h < NHEAD; h++)
      BmatT[(size_t)(h * NTOK + j) * 112 + i] = btab[r + h];
  }
}

// ---------------------------------------------------------------------------
// LN1 (fp32 input, token order) + window partition -> bf16
// ---------------------------------------------------------------------------
__global__ __launch_bounds__(256) void ln1_k(
    const float* __restrict__ x, const float* __restrict__ w,
    const float* __restrict__ b, bf16* __restrict__ o)
{
  const int wave = threadIdx.x >> 6, lane = threadIdx.x & 63;
  const int t = blockIdx.x * 4 + wave;
  const int c = lane << 1;
  float2 xv = *(const float2*)(x + (size_t)t * 128 + c);
  float x0 = xv.x, x1 = xv.y;
  float s = x0 + x1, ss = x0 * x0 + x1 * x1;
#pragma unroll
  for (int m = 32; m; m >>= 1) { s += __shfl_xor(s, m); ss += __shfl_xor(ss, m); }
  float mean = s * 0.0078125f;
  float var = ss * 0.0078125f - mean * mean;
  float rstd = rsqrtf(var + 1e-5f);
  float y0 = (x0 - mean) * rstd * w[c]     + b[c];
  float y1 = (x1 - mean) * rstd * w[c + 1] + b[c + 1];
  int wi = t % 56; int r = t / 56;
  int hi_ = r % 56; r /= 56;
  int di = r & 7; int bi = r >> 3;
  int nw = ((bi * 4 + (di >> 1)) * 8 + hi_ / 7) * 8 + wi / 7;
  int n  = ((di & 1) * 7 + hi_ % 7) * 7 + wi % 7;
  u32t ov = ((u32t)f2bfbits(y1) << 16) | (u32t)f2bfbits(y0);
  *(u32t*)((u16t*)o + (size_t)(nw * NTOK + n) * 128 + c) = ov;
}

// ---------------------------------------------------------------------------
// LN2 (bf16 input, token order) -> bf16
// ---------------------------------------------------------------------------
__global__ __launch_bounds__(256) void ln2_k(
    const bf16* __restrict__ x, const float* __restrict__ w,
    const float* __restrict__ b, bf16* __restrict__ o)
{
  const int wave = threadIdx.x >> 6, lane = threadIdx.x & 63;
  const int t = blockIdx.x * 4 + wave;
  const int c = lane << 1;
  u32t u = *(const u32t*)((const u16t*)x + (size_t)t * 128 + c);
  float x0 = bflo(u), x1 = bfhi(u);
  float s = x0 + x1, ss = x0 * x0 + x1 * x1;
#pragma unroll
  for (int m = 32; m; m >>= 1) { s += __shfl_xor(s, m); ss += __shfl_xor(ss, m); }
  float mean = s * 0.0078125f;
  float var = ss * 0.0078125f - mean * mean;
  float rstd = rsqrtf(var + 1e-5f);
  float y0 = (x0 - mean) * rstd * w[c]     + b[c];
  float y1 = (x1 - mean) * rstd * w[c + 1] + b[c + 1];
  u32t ov = ((u32t)f2bfbits(y1) << 16) | (u32t)f2bfbits(y0);
  *(u32t*)((u16t*)o + (size_t)t * 128 + c) = ov;
}

// ---------------------------------------------------------------------------
// MFMA GEMM: C[M,N] = A[M,K](bf16) @ W[N,K](bf16)^T + bias(fp32).
// 128 x (NT16*16) tile, BK=64, 4 waves. global_load_lds width=16 staging with
// XOR chunk swizzle (chunk ^= row&7) on the global source; LDS stride 64.
// MODE 0: +bias -> bf16 (NT16=4); 1: +bias+winrev+resX(f32) -> bf16 (NT16=4);
// MODE 2: +bias+GELU -> bf16 (NT16=4); 3: +bias+resB2(bf16) -> fp32 (any NT16)
// ---------------------------------------------------------------------------
template <int MODE, int NT16>
__global__ __launch_bounds__(256) void gemm_mfma_k(
    const bf16* __restrict__ A, const bf16* __restrict__ W,
    const float* __restrict__ bias, const float* __restrict__ resX,
    const bf16* __restrict__ resB2, bf16* __restrict__ outB,
    float* __restrict__ outF, int N, int K)
{
  __shared__ short As[128 * 64];
  __shared__ short Bs[NT16 * 16 * 64];
  const int tid = threadIdx.x;
  const int rowBase = blockIdx.y << 7;
  const int colBase = blockIdx.x * (NT16 * 16);
  const int wv = tid >> 6, lane = tid & 63;
  const int q = lane >> 4, r16 = lane & 15;
  const int mB = wv << 5;

  f32x4_t acc[2][NT16];
#pragma unroll
  for (int i = 0; i < 2; i++)
#pragma unroll
    for (int j = 0; j < NT16; j++) acc[i][j] = (f32x4_t){0.f, 0.f, 0.f, 0.f};

  for (int k0 = 0; k0 < K; k0 += 64) {
#pragma unroll
    for (int t = 0; t < 4; t++) {
      int f = tid + (t << 8);
      int row = f >> 3, cs = (f & 7) ^ (row & 7);
      gl_lds16((const u16t*)A + (size_t)(rowBase + row) * K + k0 + (cs << 3),
               &As[f << 3]);
    }
#pragma unroll
    for (int t = 0; t < NT16 / 2; t++) {
      int f = tid + (t << 8);
      int row = f >> 3, cs = (f & 7) ^ (row & 7);
      gl_lds16((const u16t*)W + (size_t)(colBase + row) * K + k0 + (cs << 3),
               &Bs[f << 3]);
    }
    __syncthreads();
#pragma unroll
    for (int ks = 0; ks < 2; ks++) {
      bf16x8_t af[2], bfr[NT16];
#pragma unroll
      for (int mt = 0; mt < 2; mt++) {
        int row = mB + (mt << 4) + r16;
        int ch = ((ks << 2) + q) ^ (row & 7);
        af[mt] = *(const bf16x8_t*)&As[(row << 6) + (ch << 3)];
      }
#pragma unroll
      for (int nt = 0; nt < NT16; nt++) {
        int row = (nt << 4) + r16;
        int ch = ((ks << 2) + q) ^ (row & 7);
        bfr[nt] = *(const bf16x8_t*)&Bs[(row << 6) + (ch << 3)];
      }
#pragma unroll
      for (int mt = 0; mt < 2; mt++)
#pragma unroll
        for (int nt = 0; nt < NT16; nt++)
          acc[mt][nt] = __builtin_amdgcn_mfma_f32_16x16x32_bf16(
              af[mt], bfr[nt], acc[mt][nt], 0, 0, 0);
    }
    __syncthreads();
  }

  float bv[NT16];
#pragma unroll
  for (int nt = 0; nt < NT16; nt++) bv[nt] = bias[colBase + (nt << 4) + r16];

  if (MODE == 3) {
#pragma unroll
    for (int mt = 0; mt < 2; mt++)
#pragma unroll
      for (int reg = 0; reg < 4; reg++) {
        int grow = rowBase + mB + (mt << 4) + (q << 2) + reg;
        size_t ob = (size_t)grow * N;
#pragma unroll
        for (int nt = 0; nt < NT16; nt++) {
          int gcol = colBase + (nt << 4) + r16;
          outF[ob + gcol] = acc[mt][nt][reg] + bv[nt] + bf2f(resB2[ob + gcol]);
        }
      }
    return;
  }

  // MODES 0/1/2 (NT16==4): stage C into As, then coalesced write-out.
#pragma unroll
  for (int mt = 0; mt < 2; mt++)
#pragma unroll
    for (int reg = 0; reg < 4; reg++) {
      int lrow = mB + (mt << 4) + (q << 2) + reg;
#pragma unroll
      for (int nt = 0; nt < NT16; nt++) {
        float v = acc[mt][nt][reg] + bv[nt];
        if (MODE == 2) v = 0.5f * v * (1.0f + erff(v * 0.70710678118654752f));
        As[(lrow << 6) + (nt << 4) + r16] = (short)f2bfbits(v);
      }
    }
  __syncthreads();
#pragma unroll
  for (int t = 0; t < 4; t++) {
    int f = tid + (t << 8);
    int row = f >> 3, c8 = (f & 7) << 3;
    if (MODE == 1) {
      int grow = rowBase + row;
      int nw = grow / NTOK, n = grow - nw * NTOK;
      int wq = nw & 7, hq = (nw >> 3) & 7, dq = (nw >> 6) & 3, bb = nw >> 8;
      int wr = n % 7; int q7 = n / 7; int hr = q7 % 7, dr = q7 / 7;
      int tt = ((bb * 8 + dq * 2 + dr) * 56 + hq * 7 + hr) * 56 + wq * 7 + wr;
      size_t ob = (size_t)tt * 128 + colBase + c8;
      float4 r0 = *(const float4*)(resX + ob);
      float4 r1 = *(const float4*)(resX + ob + 4);
      const short* cs = &As[(row << 6) + c8];
      u16t pk[8];
      pk[0] = f2bfbits(sh2f(cs[0]) + r0.x); pk[1] = f2bfbits(sh2f(cs[1]) + r0.y);
      pk[2] = f2bfbits(sh2f(cs[2]) + r0.z); pk[3] = f2bfbits(sh2f(cs[3]) + r0.w);
      pk[4] = f2bfbits(sh2f(cs[4]) + r1.x); pk[5] = f2bfbits(sh2f(cs[5]) + r1.y);
      pk[6] = f2bfbits(sh2f(cs[6]) + r1.z); pk[7] = f2bfbits(sh2f(cs[7]) + r1.w);
      *(uint4*)((u16t*)outB + ob) = *(const uint4*)pk;
    } else {
      size_t ob = (size_t)(rowBase + row) * N + colBase + c8;
      *(uint4*)((u16t*)outB + ob) = *(const uint4*)&As[(row << 6) + c8];
    }
  }
}

// ---------------------------------------------------------------------------
// MFMA windowed attention (round-5 shared-Ps structure + transposed-bias
// float4 loads). One block (4 waves) per (window, head).
// ---------------------------------------------------------------------------
#define PSTR 136
__global__ __launch_bounds__(256) void attn_mfma_k(
    const bf16* __restrict__ qkv, const float* __restrict__ BmatT,
    bf16* __restrict__ out)
{
  __shared__ short Vt[32 * PSTR];    // V^T [d][j], zero-padded j>=98
  __shared__ short Ps[112 * PSTR];   // P [i][j] bf16, cols 112..135 zeroed
  const int nw = blockIdx.x, h = blockIdx.y;
  const int tid = threadIdx.x;
  const int wv = tid >> 6, lane = tid & 63;
  const int q = lane >> 4, r16 = lane & 15;
  const float scale = 0.17677669529663687f;  // 32^-0.5

  for (int idx = tid; idx < 32 * 38; idx += 256) {
    int d = idx / 38, j = 98 + idx % 38;
    Vt[d * PSTR + j] = 0;
  }
  for (int idx = tid; idx < 112 * 12; idx += 256) {
    int r = idx / 12, c = (idx % 12) << 1;
    *(u32t*)&Ps[r * PSTR + 112 + c] = 0;
  }
  for (int idx = tid; idx < NTOK * 16; idx += 256) {
    int j = idx >> 4, d2 = (idx & 15) << 1;
    u32t uv = *(const u32t*)((const u16t*)qkv +
                             (size_t)(nw * NTOK + j) * 384 + 256 + h * 32 + d2);
    Vt[d2 * PSTR + j] = (short)(uv & 0xffffu);
    Vt[(d2 + 1) * PSTR + j] = (short)(uv >> 16);
  }
  __syncthreads();

  const int mt0 = wv;
  const bool has2 = (wv + 4) < 7;
  const int mt1 = has2 ? wv + 4 : wv;

  int i0 = mt0 * 16 + r16; if (i0 > NTOK - 1) i0 = NTOK - 1;
  int i1 = mt1 * 16 + r16; if (i1 > NTOK - 1) i1 = NTOK - 1;
  bf16x8_t aq0 = *(const bf16x8_t*)((const u16t*)qkv +
      (size_t)(nw * NTOK + i0) * 384 + h * 32 + (q << 3));
  bf16x8_t aq1 = *(const bf16x8_t*)((const u16t*)qkv +
      (size_t)(nw * NTOK + i1) * 384 + h * 32 + (q << 3));

  f32x4_t sc[2][7];
#pragma unroll
  for (int nt = 0; nt < 7; nt++) {
    int j = (nt << 4) + r16; if (j > NTOK - 1) j = NTOK - 1;
    bf16x8_t bk = *(const bf16x8_t*)((const u16t*)qkv +
        (size_t)(nw * NTOK + j) * 384 + 128 + h * 32 + (q << 3));
    sc[0][nt] = __builtin_amdgcn_mfma_f32_16x16x32_bf16(
        aq0, bk, (f32x4_t){0.f, 0.f, 0.f, 0.f}, 0, 0, 0);
    sc[1][nt] = __builtin_amdgcn_mfma_f32_16x16x32_bf16(
        aq1, bk, (f32x4_t){0.f, 0.f, 0.f, 0.f}, 0, 0, 0);
  }

#pragma unroll
  for (int sel = 0; sel < 2; sel++) {
    if (sel == 1 && !has2) break;
    int mtile = sel ? mt1 : mt0;
    int ibase = mtile * 16 + (q << 2);
    float s[4][7];
#pragma unroll
    for (int nt = 0; nt < 7; nt++) {
      int j = (nt << 4) + r16;
      int jc = j > NTOK - 1 ? NTOK - 1 : j;
      float4 bT = *(const float4*)&BmatT[(size_t)(h * NTOK + jc) * 112 + ibase];
      float bTa[4] = {bT.x, bT.y, bT.z, bT.w};
#pragma unroll
      for (int reg = 0; reg < 4; reg++) {
        int i = ibase + reg;
        float v = sc[sel][nt][reg] * scale;
        s[reg][nt] = (i < NTOK && j < NTOK) ? v + bTa[reg] : -1.0e30f;
      }
    }
#pragma unroll
    for (int reg = 0; reg < 4; reg++) {
      float m = -3.0e38f;
#pragma unroll
      for (int nt = 0; nt < 7; nt++) m = fmaxf(m, s[reg][nt]);
#pragma unroll
      for (int d = 8; d; d >>= 1) m = fmaxf(m, __shfl_xor(m, d));
      float sum = 0.f;
#pragma unroll
      for (int nt = 0; nt < 7; nt++) { s[reg][nt] = __expf(s[reg][nt] - m); sum += s[reg][nt]; }
#pragma unroll
      for (int d = 8; d; d >>= 1) sum += __shfl_xor(sum, d);
      float inv = 1.f / sum;
#pragma unroll
      for (int nt = 0; nt < 7; nt++)
        Ps[(ibase + reg) * PSTR + (nt << 4) + r16] =
            (short)f2bfbits(s[reg][nt] * inv);
    }
    // PV (same-wave LDS RAW, no barrier)
    f32x4_t o0 = {0.f, 0.f, 0.f, 0.f}, o1 = {0.f, 0.f, 0.f, 0.f};
#pragma unroll
    for (int kt = 0; kt < 4; kt++) {
      bf16x8_t ap = *(const bf16x8_t*)&Ps[(mtile * 16 + r16) * PSTR + (kt << 5) + (q << 3)];
      bf16x8_t bv0 = *(const bf16x8_t*)&Vt[r16 * PSTR + (kt << 5) + (q << 3)];
      bf16x8_t bv1 = *(const bf16x8_t*)&Vt[(16 + r16) * PSTR + (kt << 5) + (q << 3)];
      o0 = __builtin_amdgcn_mfma_f32_16x16x32_bf16(ap, bv0, o0, 0, 0, 0);
      o1 = __builtin_amdgcn_mfma_f32_16x16x32_bf16(ap, bv1, o1, 0, 0, 0);
    }
#pragma unroll
    for (int reg = 0; reg < 4; reg++) {
      int i = mtile * 16 + (q << 2) + reg;
      if (i < NTOK) {
        size_t ob = (size_t)(nw * NTOK + i) * 128 + h * 32;
        out[ob + r16] = f2bf(o0[reg]);
        out[ob + 16 + r16] = f2bf(o1[reg]);
      }
    }
  }
}

// ---------------------------------------------------------------------------
extern "C" void kernel_launch(void* const* d_in, const int* in_sizes, int n_in,
                              void* d_out, int out_size, void* d_ws, size_t ws_size,
                              hipStream_t stream) {
  const float* x      = (const float*)d_in[0];
  const float* n1w    = (const float*)d_in[1];
  const float* n1b    = (const float*)d_in[2];
  const float* qkv_w  = (const float*)d_in[3];
  const float* qkv_b  = (const float*)d_in[4];
  const float* btab   = (const float*)d_in[5];
  const float* proj_w = (const float*)d_in[6];
  const float* proj_b = (const float*)d_in[7];
  const float* n2w    = (const float*)d_in[8];
  const float* n2b    = (const float*)d_in[9];
  const float* fc1_w  = (const float*)d_in[10];
  const float* fc1_b  = (const float*)d_in[11];
  const float* fc2_w  = (const float*)d_in[12];
  const float* fc2_b  = (const float*)d_in[13];
  const int*   relidx = (const int*)d_in[14];

  // Layout (A = 50176*128*2 B = 12,845,056):
  //   ws[0, 384K):      bf16 weights
  //   ws[384K, ~556K):  BmatT fp32 (4*98*112)
  //   R = ws+1MB:       qkv [R, R+3A) -> x2 [R, R+A), xn2 [R+A, R+2A),
  //                     hmid [R+2A, +A or +4A depending on ws_size)
  //   d_out scratch: xw = attn = d_out[0,A) (dead before final fp32 write)
  const size_t Asz = (size_t)TOK * 128 * 2;
  char* ws = (char*)d_ws;
  bf16* wbf   = (bf16*)ws;
  bf16* qkvw16  = wbf;               // 49152
  bf16* projw16 = wbf + 49152;       // 16384
  bf16* fc1w16  = wbf + 65536;       // 65536
  bf16* fc2w16  = wbf + 131072;      // 65536
  float* BmatT = (float*)(ws + 393216);
  char* R = ws + (1 << 20);
  bf16* xw    = (bf16*)d_out;
  bf16* attn  = (bf16*)d_out;
  bf16* qkv   = (bf16*)R;
  bf16* x2    = (bf16*)R;
  bf16* xn2   = (bf16*)(R + Asz);
  bf16* hmid  = (bf16*)(R + 2 * Asz);
  float* out  = (float*)d_out;
  const bool fullM = ws_size >= ((size_t)(1 << 20) + 6 * Asz);

  // 0. weight conversion + transposed bias matrix
  cvt4_k<<<768, 256, 0, stream>>>(qkv_w, proj_w, fc1_w, fc2_w, wbf);
  bias_k<<<38, 256, 0, stream>>>(btab, relidx, BmatT);
  // 1. LN1 + window partition
  ln1_k<<<TOK / 4, 256, 0, stream>>>(x, n1w, n1b, xw);
  // 2. QKV: (50176,128) @ (384,128)^T
  gemm_mfma_k<0, 4><<<dim3(6, TOK / 128), 256, 0, stream>>>(
      xw, qkvw16, qkv_b, nullptr, nullptr, qkv, nullptr, 384, 128);
  // 3. MFMA windowed attention
  attn_mfma_k<<<dim3(NWIN, NHEAD), 256, 0, stream>>>(qkv, BmatT, attn);
  // 4. proj + window reverse + residual(x fp32) -> x2 bf16 (token order)
  gemm_mfma_k<1, 4><<<dim3(2, TOK / 128), 256, 0, stream>>>(
      attn, projw16, proj_b, x, nullptr, x2, nullptr, 128, 128);
  // 5. LN2
  ln2_k<<<TOK / 4, 256, 0, stream>>>(x2, n2w, n2b, xn2);
  // 6/7. MLP
  if (fullM) {
    gemm_mfma_k<2, 4><<<dim3(8, TOK / 128), 256, 0, stream>>>(
        xn2, fc1w16, fc1_b, nullptr, nullptr, hmid, nullptr, 512, 128);
    gemm_mfma_k<3, 8><<<dim3(1, TOK / 128), 256, 0, stream>>>(
        hmid, fc2w16, fc2_b, nullptr, x2, nullptr, out, 128, 512);
  } else {
    const int MC = TOK / 4;  // 12544 rows per chunk
    for (int c = 0; c < 4; c++) {
      gemm_mfma_k<2, 4><<<dim3(8, MC / 128), 256, 0, stream>>>(
          xn2 + (size_t)c * MC * 128, fc1w16, fc1_b, nullptr, nullptr,
          hmid, nullptr, 512, 128);
      gemm_mfma_k<3, 4><<<dim3(2, MC / 128), 256, 0, stream>>>(
          hmid, fc2w16, fc2_b, nullptr, x2 + (size_t)c * MC * 128,
          nullptr, out + (size_t)c * MC * 128, 128, 512);
    }
  }
}